// Round 1
// baseline (714.149 us; speedup 1.0000x reference)
//
#include <hip/hip_runtime.h>
#include <hip/hip_bf16.h>
#include <stdint.h>

#define BB 8
#define NN 2048
#define DD 1024
#define HH 1024
#define M_TOT (BB*NN)   // 16384

using f32x4 = __attribute__((ext_vector_type(4))) float;
using s16x8 = __attribute__((ext_vector_type(8))) short;

__device__ __forceinline__ short f2bf(float f){
  union { float f; uint32_t u; } v; v.f = f;
  uint32_t r = (v.u + 0x7fffu + ((v.u >> 16) & 1u)) >> 16;
  return (short)r;
}

#define MFMA(a,b,c) __builtin_amdgcn_mfma_f32_16x16x32_bf16((a),(b),(c),0,0,0)

// async global->LDS, 16B per lane. LDS dest is wave-uniform-base + lane*16.
#define GL16(gp, lp) __builtin_amdgcn_global_load_lds( \
    (const __attribute__((address_space(1))) void*)(gp), \
    (__attribute__((address_space(3))) void*)(lp), 16, 0, 0)

// ---------------- kernel 0a: x fp32 -> bf16 ----------------
__global__ __launch_bounds__(256) void k_conv_x(const float* __restrict__ x,
                                                short* __restrict__ xb){
  int gid = blockIdx.x*256 + threadIdx.x;           // 2,097,152 threads, 8 elems each
  const float4* xv = (const float4*)x;
  float4 a = xv[(size_t)gid*2], b2 = xv[(size_t)gid*2+1];
  s16x8 o;
  o[0]=f2bf(a.x);  o[1]=f2bf(a.y);  o[2]=f2bf(a.z);  o[3]=f2bf(a.w);
  o[4]=f2bf(b2.x); o[5]=f2bf(b2.y); o[6]=f2bf(b2.z); o[7]=f2bf(b2.w);
  *(s16x8*)(xb + (size_t)gid*8) = o;
}

// ---------------- kernel 0b: pack W^T bf16 [3072][1024] ----------------
__global__ __launch_bounds__(256) void k_conv_w(const float* __restrict__ Wq,
                                                const float* __restrict__ Wk,
                                                const float* __restrict__ Wv,
                                                short* __restrict__ Wt){
  __shared__ float tile[64][65];
  int bx = blockIdx.x; int mat = bx >> 8; int ti = bx & 255;
  int d0 = (ti >> 4) << 6, h0 = (ti & 15) << 6;
  const float* W = (mat==0) ? Wq : (mat==1 ? Wk : Wv);
  int t = threadIdx.x;
  for (int i=0;i<16;i++){ int e = i*256 + t; int r = e>>6, c = e&63;
    tile[r][c] = W[(size_t)(d0+r)*HH + h0 + c]; }
  __syncthreads();
  for (int i=0;i<16;i++){ int e = i*256 + t; int r = e>>6, c = e&63;
    Wt[(size_t)(mat*HH + h0 + r)*DD + d0 + c] = f2bf(tile[c][r]); }
}

// ---------------- kernel 1: GEMM  C[16384 x 3072] = xb * W  (+bias), bf16 out ----
// A = xb [16384][1024] row-major, B^T = Wt [3072][1024] row-major.
// 128x128 tile, 4 waves (2x2), 4x4 16x16x32 frags per wave, BK=32, gload_lds w16.
__global__ __launch_bounds__(256) void k_gemm(const short* __restrict__ Aw,
                                              const short* __restrict__ Bw,
                                              const float* __restrict__ bq,
                                              const float* __restrict__ bk,
                                              const float* __restrict__ bv,
                                              short* __restrict__ Qw,
                                              short* __restrict__ Kw,
                                              short* __restrict__ Vw){
  __shared__ short Al[128*32];
  __shared__ short Bl[128*32];
  int t = threadIdx.x; int l = t & 63; int w = t >> 6;
  int bn = blockIdx.x, bm = blockIdx.y;
  int m0 = bm << 7, c0 = bn << 7;
  f32x4 acc[4][4] = {};
  int soff = w*2048 + l*16;
  int rA0 = ((w>>1)*64 + (l&15))*32 + (l>>4)*8;
  int rB0 = ((w&1)*64 + (l&15))*32 + (l>>4)*8;
  for (int k0 = 0; k0 < DD; k0 += 32){
    __syncthreads();
    #pragma unroll
    for (int j=0;j<2;j++){
      int off = soff + j*1024;
      int row = off >> 6, ke = (off & 63) >> 1;
      GL16(Aw + (size_t)(m0+row)*DD + k0 + ke, ((char*)Al) + off);
      GL16(Bw + (size_t)(c0+row)*DD + k0 + ke, ((char*)Bl) + off);
    }
    __syncthreads();
    s16x8 af[4], bf[4];
    #pragma unroll
    for (int i=0;i<4;i++){
      af[i] = *(const s16x8*)&Al[rA0 + i*512];
      bf[i] = *(const s16x8*)&Bl[rB0 + i*512];
    }
    #pragma unroll
    for (int mi=0;mi<4;mi++)
      #pragma unroll
      for (int ni=0;ni<4;ni++)
        acc[mi][ni] = MFMA(af[mi], bf[ni], acc[mi][ni]);
  }
  // epilogue: bias + bf16 store into Q/K/V (C/D layout: col=lane&15, row=(lane>>4)*4+i)
  int wr = w>>1, wc = w&1;
  int rg_base = m0 + wr*64;
  int cg_base = c0 + wc*64;
  #pragma unroll
  for (int ni=0;ni<4;ni++){
    int cg = cg_base + ni*16 + (l&15);
    int mat = cg >> 10, cin = cg & 1023;
    const float* bias = (mat==0) ? bq : (mat==1 ? bk : bv);
    float bval = bias[cin];
    short* Outp = (mat==0) ? Qw : (mat==1 ? Kw : Vw);
    #pragma unroll
    for (int mi=0;mi<4;mi++){
      int rg = rg_base + mi*16 + (l>>4)*4;
      #pragma unroll
      for (int i=0;i<4;i++)
        Outp[(size_t)(rg+i)*HH + cin] = f2bf(acc[mi][ni][i] + bval);
    }
  }
}

// ---------------- kernel 1b: V [b][n][h] -> Vt [b][h][n] ----------------
__global__ __launch_bounds__(256) void k_vtrans(const short* __restrict__ Vw,
                                                short* __restrict__ Vt){
  __shared__ uint16_t tile[64][65];
  int bx = blockIdx.x; int b = bx >> 9; int rem = bx & 511;
  int n0 = (rem >> 4) << 6, h0 = (rem & 15) << 6;
  int t = threadIdx.x;
  const uint16_t* vin = (const uint16_t*)Vw;
  uint16_t* vout = (uint16_t*)Vt;
  for (int i=0;i<16;i++){ int e = i*256 + t; int r = e>>6, c = e&63;
    tile[r][c] = vin[((size_t)b*NN + n0 + r)*HH + h0 + c]; }
  __syncthreads();
  for (int i=0;i<16;i++){ int e = i*256 + t; int r = e>>6, c = e&63;
    vout[((size_t)b*HH + h0 + r)*NN + n0 + c] = tile[c][r]; }
}

// ---------------- kernel 2: flash attention ----------------
// 512 threads = 8 waves. Block owns 32 q-rows; wave w owns h-slice [w*128,(w+1)*128).
// Per key-tile (32 keys): per-wave QK^T partial over its h-slice -> LDS reduce ->
// online softmax (16 lanes per row) -> P bf16 (swizzled LDS) -> per-wave PV into
// O[32 x 128] (64 VGPRs). K frags from global (row-major), V frags from Vt.
__global__ __launch_bounds__(512,2) void k_flash(const short* __restrict__ Qw,
                                                 const short* __restrict__ Kw,
                                                 const short* __restrict__ Vt,
                                                 float* __restrict__ out){
  __shared__ float Sred[8][32][34];     // padded: reduce reads conflict-free
  __shared__ uint16_t Pl[32*64];        // rows 128B, XOR-swizzled
  __shared__ float m_l[32], l_l[32], f_l[32];
  int t = threadIdx.x, l = t & 63, w = t >> 6;
  int p = blockIdx.x; int b = p >> 6; int q_phys = p & 63;
  int qt = (b & 4) ? (63 - q_phys) : q_phys;   // causal load-balance pairing
  int q0 = qt << 5;
  const float scale = 0.03125f;          // 1/sqrt(1024)
  const float L2E = 1.44269504088896f;
  const float NEG = -__builtin_inff();

  // resident Q fragments: A-frag lane: q-row = l&15, h-chunk = (l>>4)*8
  s16x8 qf[2][4];
  #pragma unroll
  for (int qi=0;qi<2;qi++)
    #pragma unroll
    for (int hs=0;hs<4;hs++)
      qf[qi][hs] = *(const s16x8*)(Qw + ((size_t)b*NN + q0 + qi*16 + (l&15))*HH
                                      + w*128 + hs*32 + (l>>4)*8);
  f32x4 o[2][8] = {};
  if (t < 32){ m_l[t] = NEG; l_l[t] = 0.f; }
  __syncthreads();
  int r_red = t >> 4, j_red = t & 15;

  for (int kt = 0; kt <= qt; kt++){
    int k0 = kt << 5;
    // ---- QK^T partial over this wave's h-slice ----
    f32x4 sp[2][2] = {};
    #pragma unroll
    for (int hs=0; hs<4; hs++){
      #pragma unroll
      for (int ki=0; ki<2; ki++){
        s16x8 kf = *(const s16x8*)(Kw + ((size_t)b*NN + k0 + ki*16 + (l&15))*HH
                                      + w*128 + hs*32 + (l>>4)*8);
        #pragma unroll
        for (int qi=0;qi<2;qi++)
          sp[qi][ki] = MFMA(qf[qi][hs], kf, sp[qi][ki]);
      }
    }
    #pragma unroll
    for (int qi=0;qi<2;qi++)
      #pragma unroll
      for (int ki=0;ki<2;ki++)
        #pragma unroll
        for (int i=0;i<4;i++)
          Sred[w][qi*16 + (l>>4)*4 + i][ki*16 + (l&15)] = sp[qi][ki][i];
    __syncthreads();
    // ---- reduce across waves + online softmax: 16 threads per row, 2 cols each ----
    {
      float s0 = 0.f, s1 = 0.f;
      #pragma unroll
      for (int ww=0; ww<8; ww++){
        s0 += Sred[ww][r_red][2*j_red];
        s1 += Sred[ww][r_red][2*j_red+1];
      }
      s0 *= scale; s1 *= scale;
      if (kt == qt){
        if (2*j_red   > r_red) s0 = NEG;
        if (2*j_red+1 > r_red) s1 = NEG;
      }
      float tm = fmaxf(s0, s1);
      #pragma unroll
      for (int d=1; d<16; d<<=1) tm = fmaxf(tm, __shfl_xor(tm, d, 16));
      float mo = m_l[r_red];
      float mn = fmaxf(mo, tm);
      float p0 = exp2f((s0 - mn)*L2E);
      float p1 = exp2f((s1 - mn)*L2E);
      float fsc = exp2f((mo - mn)*L2E);
      float ps = p0 + p1;
      #pragma unroll
      for (int d=1; d<16; d<<=1) ps += __shfl_xor(ps, d, 16);
      if (j_red == 0){ m_l[r_red] = mn; l_l[r_red] = l_l[r_red]*fsc + ps; f_l[r_red] = fsc; }
      uint32_t pk = ((uint32_t)(uint16_t)f2bf(p1) << 16) | (uint16_t)f2bf(p0);
      int off = (r_red*128 + j_red*4) ^ ((r_red & 7) << 4);
      *(uint32_t*)((char*)Pl + off) = pk;
    }
    __syncthreads();
    // ---- PV: rescale O, then accumulate P * V over this tile ----
    float fr[2][4];
    #pragma unroll
    for (int qi=0;qi<2;qi++)
      #pragma unroll
      for (int i=0;i<4;i++) fr[qi][i] = f_l[qi*16 + (l>>4)*4 + i];
    s16x8 pf[2];
    #pragma unroll
    for (int qi=0;qi<2;qi++){
      int q = qi*16 + (l&15);
      int poff = (q*128 + (l>>4)*16) ^ ((q & 7) << 4);
      pf[qi] = *(const s16x8*)((char*)Pl + poff);
    }
    #pragma unroll
    for (int qi=0;qi<2;qi++)
      #pragma unroll
      for (int hi=0;hi<8;hi++)
        #pragma unroll
        for (int i=0;i<4;i++) o[qi][hi][i] *= fr[qi][i];
    #pragma unroll
    for (int hi=0;hi<8;hi++){
      s16x8 vf = *(const s16x8*)(Vt + ((size_t)b*HH + w*128 + hi*16 + (l&15))*NN
                                    + k0 + (l>>4)*8);
      #pragma unroll
      for (int qi=0;qi<2;qi++)
        o[qi][hi] = MFMA(pf[qi], vf, o[qi][hi]);
    }
  }
  // ---- epilogue: O / l ----
  float inv[2][4];
  #pragma unroll
  for (int qi=0;qi<2;qi++)
    #pragma unroll
    for (int i=0;i<4;i++) inv[qi][i] = 1.0f / l_l[qi*16 + (l>>4)*4 + i];
  #pragma unroll
  for (int qi=0;qi<2;qi++)
    #pragma unroll
    for (int hi=0;hi<8;hi++)
      #pragma unroll
      for (int i=0;i<4;i++){
        int row = q0 + qi*16 + (l>>4)*4 + i;
        int h = w*128 + hi*16 + (l&15);
        out[((size_t)b*NN + row)*HH + h] = o[qi][hi][i] * inv[qi][i];
      }
}

extern "C" void kernel_launch(void* const* d_in, const int* in_sizes, int n_in,
                              void* d_out, int out_size, void* d_ws, size_t ws_size,
                              hipStream_t stream) {
  const float* x  = (const float*)d_in[0];
  const float* Wq = (const float*)d_in[1];
  const float* bq = (const float*)d_in[2];
  const float* Wk = (const float*)d_in[3];
  const float* bk = (const float*)d_in[4];
  const float* Wv = (const float*)d_in[5];
  const float* bv = (const float*)d_in[6];
  char* ws = (char*)d_ws;
  // ws layout (bytes), total ~174 MB
  short* xb = (short*)(ws);                         // 33,554,432
  short* Wt = (short*)(ws + 33554432u);             //  6,291,456
  short* Qw = (short*)(ws + 39845888u);             // 33,554,432
  short* Kw = (short*)(ws + 73400320u);             // 33,554,432
  short* Vw = (short*)(ws + 106954752u);            // 33,554,432
  short* Vt = (short*)(ws + 140509184u);            // 33,554,432

  k_conv_x<<<8192, 256, 0, stream>>>(x, xb);
  k_conv_w<<<768, 256, 0, stream>>>(Wq, Wk, Wv, Wt);
  k_gemm<<<dim3(24,128), 256, 0, stream>>>(xb, Wt, bq, bk, bv, Qw, Kw, Vw);
  k_vtrans<<<4096, 256, 0, stream>>>(Vw, Vt);
  k_flash<<<512, 512, 0, stream>>>(Qw, Kw, Vt, (float*)d_out);
}

// Round 2
// 550.855 us; speedup vs baseline: 1.2964x; 1.2964x over previous
//
#include <hip/hip_runtime.h>
#include <hip/hip_bf16.h>
#include <stdint.h>

#define BB 8
#define NN 2048
#define DD 1024
#define HH 1024

using f32x4 = __attribute__((ext_vector_type(4))) float;
using s16x8 = __attribute__((ext_vector_type(8))) short;

__device__ __forceinline__ short f2bf(float f){
  union { float f; uint32_t u; } v; v.f = f;
  uint32_t r = (v.u + 0x7fffu + ((v.u >> 16) & 1u)) >> 16;
  return (short)r;
}

#define MFMA(a,b,c) __builtin_amdgcn_mfma_f32_16x16x32_bf16((a),(b),(c),0,0,0)

// async global->LDS, 16B per lane. LDS dest is wave-uniform base + lane*16;
// global source IS per-lane (pre-swizzle the source for swizzled LDS layouts).
#define GL16(gp, lp) __builtin_amdgcn_global_load_lds( \
    (const __attribute__((address_space(1))) void*)(gp), \
    (__attribute__((address_space(3))) void*)(lp), 16, 0, 0)

// ---------------- kernel 0a: x fp32 -> bf16 ----------------
__global__ __launch_bounds__(256) void k_conv_x(const float* __restrict__ x,
                                                short* __restrict__ xb){
  int gid = blockIdx.x*256 + threadIdx.x;
  const float4* xv = (const float4*)x;
  float4 a = xv[(size_t)gid*2], b2 = xv[(size_t)gid*2+1];
  s16x8 o;
  o[0]=f2bf(a.x);  o[1]=f2bf(a.y);  o[2]=f2bf(a.z);  o[3]=f2bf(a.w);
  o[4]=f2bf(b2.x); o[5]=f2bf(b2.y); o[6]=f2bf(b2.z); o[7]=f2bf(b2.w);
  *(s16x8*)(xb + (size_t)gid*8) = o;
}

// ---------------- kernel 0b: pack W^T bf16 [3072][1024] ----------------
__global__ __launch_bounds__(256) void k_conv_w(const float* __restrict__ Wq,
                                                const float* __restrict__ Wk,
                                                const float* __restrict__ Wv,
                                                short* __restrict__ Wt){
  __shared__ float tile[64][65];
  int bx = blockIdx.x; int mat = bx >> 8; int ti = bx & 255;
  int d0 = (ti >> 4) << 6, h0 = (ti & 15) << 6;
  const float* W = (mat==0) ? Wq : (mat==1 ? Wk : Wv);
  int t = threadIdx.x;
  for (int i=0;i<16;i++){ int e = i*256 + t; int r = e>>6, c = e&63;
    tile[r][c] = W[(size_t)(d0+r)*HH + h0 + c]; }
  __syncthreads();
  for (int i=0;i<16;i++){ int e = i*256 + t; int r = e>>6, c = e&63;
    Wt[(size_t)(mat*HH + h0 + r)*DD + d0 + c] = f2bf(tile[c][r]); }
}

// ---------------- kernel 1: GEMM  C[16384 x 3072] = xb * W  (+bias), bf16 out ----
__global__ __launch_bounds__(256) void k_gemm(const short* __restrict__ Aw,
                                              const short* __restrict__ Bw,
                                              const float* __restrict__ bq,
                                              const float* __restrict__ bk,
                                              const float* __restrict__ bv,
                                              short* __restrict__ Qw,
                                              short* __restrict__ Kw,
                                              short* __restrict__ Vw){
  __shared__ short Al[128*32];
  __shared__ short Bl[128*32];
  int t = threadIdx.x; int l = t & 63; int w = t >> 6;
  int bn = blockIdx.x, bm = blockIdx.y;
  int m0 = bm << 7, c0 = bn << 7;
  f32x4 acc[4][4] = {};
  int soff = w*2048 + l*16;
  int rA0 = ((w>>1)*64 + (l&15))*32 + (l>>4)*8;
  int rB0 = ((w&1)*64 + (l&15))*32 + (l>>4)*8;
  for (int k0 = 0; k0 < DD; k0 += 32){
    __syncthreads();
    #pragma unroll
    for (int j=0;j<2;j++){
      int off = soff + j*1024;
      int row = off >> 6, ke = (off & 63) >> 1;
      GL16(Aw + (size_t)(m0+row)*DD + k0 + ke, ((char*)Al) + off);
      GL16(Bw + (size_t)(c0+row)*DD + k0 + ke, ((char*)Bl) + off);
    }
    __syncthreads();
    s16x8 af[4], bf[4];
    #pragma unroll
    for (int i=0;i<4;i++){
      af[i] = *(const s16x8*)&Al[rA0 + i*512];
      bf[i] = *(const s16x8*)&Bl[rB0 + i*512];
    }
    #pragma unroll
    for (int mi=0;mi<4;mi++)
      #pragma unroll
      for (int ni=0;ni<4;ni++)
        acc[mi][ni] = MFMA(af[mi], bf[ni], acc[mi][ni]);
  }
  int wr = w>>1, wc = w&1;
  int rg_base = m0 + wr*64;
  int cg_base = c0 + wc*64;
  #pragma unroll
  for (int ni=0;ni<4;ni++){
    int cg = cg_base + ni*16 + (l&15);
    int mat = cg >> 10, cin = cg & 1023;
    const float* bias = (mat==0) ? bq : (mat==1 ? bk : bv);
    float bval = bias[cin];
    short* Outp = (mat==0) ? Qw : (mat==1 ? Kw : Vw);
    #pragma unroll
    for (int mi=0;mi<4;mi++){
      int rg = rg_base + mi*16 + (l>>4)*4;
      #pragma unroll
      for (int i=0;i<4;i++)
        Outp[(size_t)(rg+i)*HH + cin] = f2bf(acc[mi][ni][i] + bval);
    }
  }
}

// ---------------- kernel 1b: V [b][n][h] -> Vt [b][h][n] ----------------
__global__ __launch_bounds__(256) void k_vtrans(const short* __restrict__ Vw,
                                                short* __restrict__ Vt){
  __shared__ uint16_t tile[64][65];
  int bx = blockIdx.x; int b = bx >> 9; int rem = bx & 511;
  int n0 = (rem >> 4) << 6, h0 = (rem & 15) << 6;
  int t = threadIdx.x;
  const uint16_t* vin = (const uint16_t*)Vw;
  uint16_t* vout = (uint16_t*)Vt;
  for (int i=0;i<16;i++){ int e = i*256 + t; int r = e>>6, c = e&63;
    tile[r][c] = vin[((size_t)b*NN + n0 + r)*HH + h0 + c]; }
  __syncthreads();
  for (int i=0;i<16;i++){ int e = i*256 + t; int r = e>>6, c = e&63;
    vout[((size_t)b*HH + h0 + r)*NN + n0 + c] = tile[c][r]; }
}

// ---------------- kernel 2: flash attention v2 ----------------
// 256 blocks (b = blk&7 -> XCD-pinned batch, qt = blk>>3), 512 threads = 8 waves.
// Block owns BQ=64 q-rows. Iteration = 256 keys; wave w owns keys [w*32,(w+1)*32)
// for QK^T (full H, S in regs, transposed mfma(K,Q)) and h-slice [w*128,(w+1)*128)
// for PV (O[64x128] in regs = 128 VGPR). Q staged in LDS per 256-col chunk via
// global_load_lds with XOR-swizzled source; only m/l cross waves (tiny LDS reduce).
__global__ __launch_bounds__(512,2) void k_flash(const short* __restrict__ Qw,
                                                 const short* __restrict__ Kw,
                                                 const short* __restrict__ Vt,
                                                 float* __restrict__ out){
  __shared__ short Qc[2][64*256];      // 64 KiB, double-buffered Q chunk
  __shared__ uint16_t Pl[64*264];      // 33 KiB, P[64][264] (pad 8 -> 8-window reads)
  __shared__ float Mred[8][64];        // per-wave partial max / (epilogue) l partials
  __shared__ float Mfin[64], Fsc[64], Mst[64], Lfin[64];

  const int t = threadIdx.x, l = t & 63, w = t >> 6;
  const int g = l >> 4, c = l & 15;
  const int p = blockIdx.x;
  const int b = p & 7, qt = p >> 3;
  const int q0 = qt << 6;
  const float scale = 0.03125f;              // 1/sqrt(1024)
  const float L2E = 1.44269504088896f;
  const float NEG = -3.0e38f;                // finite: fully-masked rows self-correct

  f32x4 o[4][8] = {};
  float lp[4] = {0.f, 0.f, 0.f, 0.f};
  if (t < 64) Mst[t] = NEG;

  auto stage_chunk = [&](int chunk, int buf){
    #pragma unroll
    for (int j=0;j<4;j++){
      int r = w*8 + 2*j + (l>>5);
      int u = (l & 31) ^ (r & 7);            // inverse read-swizzle on the source
      GL16(Qw + ((size_t)(b*NN + q0 + r))*HH + chunk*256 + u*8,
           ((char*)&Qc[buf][0]) + (w*8 + 2*j)*512);
    }
  };

  stage_chunk(0, 0);
  const int n_it = (qt + 4) >> 2;
  for (int it = 0; it < n_it; ++it){
    const int kb = it*256 + w*32;            // wave's first key this iteration
    const bool active = kb <= q0 + 63;
    f32x4 sp[4][2] = {};
    for (int hc = 0; hc < 4; ++hc){
      asm volatile("s_waitcnt vmcnt(0)" ::: "memory");
      __syncthreads();
      if (hc < 3 || it + 1 < n_it) stage_chunk((hc+1)&3, (hc+1)&1);
      if (active){
        const short* Kp = Kw + ((size_t)(b*NN + kb + c))*HH + hc*256;
        __builtin_amdgcn_s_setprio(1);
        #pragma unroll
        for (int hs = 0; hs < 8; ++hs){
          s16x8 kf0 = *(const s16x8*)(Kp + hs*32 + g*8);
          s16x8 kf1 = *(const s16x8*)(Kp + (size_t)16*HH + hs*32 + g*8);
          #pragma unroll
          for (int qi = 0; qi < 4; ++qi){
            int r = qi*16 + c;
            s16x8 qf = *(const s16x8*)&Qc[hc&1][r*256 + (((hs*4+g) ^ (r&7))*8)];
            sp[qi][0] = MFMA(kf0, qf, sp[qi][0]);   // S^T: rows=key, cols=q
            sp[qi][1] = MFMA(kf1, qf, sp[qi][1]);
          }
        }
        __builtin_amdgcn_s_setprio(0);
      }
    }
    // ---- softmax. S^T C/D layout: key = kb + ki*16 + g*4 + i, q = q0 + qi*16 + c.
    float rmax[4];
    #pragma unroll
    for (int qi=0;qi<4;qi++){
      int q = q0 + qi*16 + c;
      float mx = NEG;
      #pragma unroll
      for (int ki=0;ki<2;ki++)
        #pragma unroll
        for (int i=0;i<4;i++){
          int key = kb + ki*16 + g*4 + i;
          float s = (key <= q) ? sp[qi][ki][i]*scale : NEG;
          sp[qi][ki][i] = s;
          mx = fmaxf(mx, s);
        }
      rmax[qi] = mx;
    }
    #pragma unroll
    for (int qi=0;qi<4;qi++){
      rmax[qi] = fmaxf(rmax[qi], __shfl_xor(rmax[qi], 16));
      rmax[qi] = fmaxf(rmax[qi], __shfl_xor(rmax[qi], 32));
    }
    if (g == 0){
      #pragma unroll
      for (int qi=0;qi<4;qi++) Mred[w][qi*16 + c] = rmax[qi];
    }
    __syncthreads();
    if (t < 64){
      float mx = Mred[0][t];
      #pragma unroll
      for (int ww=1; ww<8; ww++) mx = fmaxf(mx, Mred[ww][t]);
      float mo = Mst[t];
      float mn = fmaxf(mo, mx);
      Mst[t] = mn; Mfin[t] = mn;
      Fsc[t] = exp2f((mo - mn)*L2E);         // mo==mn==NEG -> 1.0 (O is 0, benign)
    }
    __syncthreads();
    // exp + per-wave row-sum + P write (b64, 4 consecutive cols per store)
    #pragma unroll
    for (int qi=0;qi<4;qi++){
      float mf = Mfin[qi*16 + c];
      float sum = 0.f;
      #pragma unroll
      for (int ki=0;ki<2;ki++){
        short4 pk;
        #pragma unroll
        for (int i=0;i<4;i++){
          float pv = exp2f((sp[qi][ki][i] - mf)*L2E);
          sum += pv;
          ((short*)&pk)[i] = f2bf(pv);
        }
        *(short4*)((char*)Pl + (qi*16 + c)*528 + (size_t)(w*32 + ki*16 + g*4)*2) = pk;
      }
      sum += __shfl_xor(sum, 16);
      sum += __shfl_xor(sum, 32);
      lp[qi] = lp[qi]*Fsc[qi*16 + c] + sum;
    }
    // rescale O (O C/D rows: q = qi*16 + g*4 + i)
    #pragma unroll
    for (int qi=0;qi<4;qi++){
      f32x4 fs = *(const f32x4*)&Fsc[qi*16 + g*4];
      #pragma unroll
      for (int hi=0;hi<8;hi++)
        #pragma unroll
        for (int i=0;i<4;i++) o[qi][hi][i] *= fs[i];
    }
    __syncthreads();                          // P ready
    // ---- PV: O[64 x 128] += P[64 x 256] * V ----
    __builtin_amdgcn_s_setprio(1);
    #pragma unroll
    for (int kt=0; kt<8; ++kt){
      s16x8 pf[4];
      #pragma unroll
      for (int qi=0;qi<4;qi++)
        pf[qi] = *(const s16x8*)((char*)Pl + (qi*16 + c)*528 + (size_t)(kt*32 + g*8)*2);
      #pragma unroll
      for (int hi=0;hi<8;hi++){
        s16x8 vf = *(const s16x8*)(Vt + ((size_t)(b*HH + w*128 + hi*16 + c))*NN
                                      + it*256 + kt*32 + g*8);
        #pragma unroll
        for (int qi=0;qi<4;qi++)
          o[qi][hi] = MFMA(pf[qi], vf, o[qi][hi]);
      }
    }
    __builtin_amdgcn_s_setprio(0);
  }
  // ---- epilogue: reduce l across waves, divide, store ----
  if (g == 0){
    #pragma unroll
    for (int qi=0;qi<4;qi++) Mred[w][qi*16 + c] = lp[qi];
  }
  __syncthreads();
  if (t < 64){
    float s = 0.f;
    #pragma unroll
    for (int ww=0; ww<8; ww++) s += Mred[ww][t];
    Lfin[t] = 1.0f / s;
  }
  __syncthreads();
  #pragma unroll
  for (int qi=0;qi<4;qi++){
    f32x4 li = *(const f32x4*)&Lfin[qi*16 + g*4];
    #pragma unroll
    for (int hi=0;hi<8;hi++)
      #pragma unroll
      for (int i=0;i<4;i++)
        out[((size_t)(b*NN + q0 + qi*16 + g*4 + i))*HH + w*128 + hi*16 + c]
          = o[qi][hi][i] * li[i];
  }
}

extern "C" void kernel_launch(void* const* d_in, const int* in_sizes, int n_in,
                              void* d_out, int out_size, void* d_ws, size_t ws_size,
                              hipStream_t stream) {
  const float* x  = (const float*)d_in[0];
  const float* Wq = (const float*)d_in[1];
  const float* bq = (const float*)d_in[2];
  const float* Wk = (const float*)d_in[3];
  const float* bk = (const float*)d_in[4];
  const float* Wv = (const float*)d_in[5];
  const float* bv = (const float*)d_in[6];
  char* ws = (char*)d_ws;
  short* xb = (short*)(ws);                         // 33,554,432
  short* Wt = (short*)(ws + 33554432u);             //  6,291,456
  short* Qw = (short*)(ws + 39845888u);             // 33,554,432
  short* Kw = (short*)(ws + 73400320u);             // 33,554,432
  short* Vw = (short*)(ws + 106954752u);            // 33,554,432
  short* Vt = (short*)(ws + 140509184u);            // 33,554,432

  k_conv_x<<<8192, 256, 0, stream>>>(x, xb);
  k_conv_w<<<768, 256, 0, stream>>>(Wq, Wk, Wv, Wt);
  k_gemm<<<dim3(24,128), 256, 0, stream>>>(xb, Wt, bq, bk, bv, Qw, Kw, Vw);
  k_vtrans<<<4096, 256, 0, stream>>>(Vw, Vt);
  k_flash<<<256, 512, 0, stream>>>(Qw, Kw, Vt, (float*)d_out);
}

// Round 3
// 417.433 us; speedup vs baseline: 1.7108x; 1.3196x over previous
//
#include <hip/hip_runtime.h>
#include <hip/hip_bf16.h>
#include <stdint.h>

#define BB 8
#define NN 2048
#define DD 1024
#define HH 1024

using f32x4 = __attribute__((ext_vector_type(4))) float;
using s16x8 = __attribute__((ext_vector_type(8))) short;

__device__ __forceinline__ short f2bf(float f){
  union { float f; uint32_t u; } v; v.f = f;
  uint32_t r = (v.u + 0x7fffu + ((v.u >> 16) & 1u)) >> 16;
  return (short)r;
}

#define MFMA(a,b,c) __builtin_amdgcn_mfma_f32_16x16x32_bf16((a),(b),(c),0,0,0)

// async global->LDS, 16B per lane. LDS dest is wave-uniform base + lane*16;
// global source IS per-lane (pre-swizzle the source for swizzled LDS layouts).
#define GL16(gp, lp) __builtin_amdgcn_global_load_lds( \
    (const __attribute__((address_space(1))) void*)(gp), \
    (__attribute__((address_space(3))) void*)(lp), 16, 0, 0)

// ---------------- kernel 0a: x fp32 -> bf16 ----------------
__global__ __launch_bounds__(256) void k_conv_x(const float* __restrict__ x,
                                                short* __restrict__ xb){
  int gid = blockIdx.x*256 + threadIdx.x;
  const float4* xv = (const float4*)x;
  float4 a = xv[(size_t)gid*2], b2 = xv[(size_t)gid*2+1];
  s16x8 o;
  o[0]=f2bf(a.x);  o[1]=f2bf(a.y);  o[2]=f2bf(a.z);  o[3]=f2bf(a.w);
  o[4]=f2bf(b2.x); o[5]=f2bf(b2.y); o[6]=f2bf(b2.z); o[7]=f2bf(b2.w);
  *(s16x8*)(xb + (size_t)gid*8) = o;
}

// ---------------- kernel 0b: pack W^T bf16 [3072][1024] ----------------
__global__ __launch_bounds__(256) void k_conv_w(const float* __restrict__ Wq,
                                                const float* __restrict__ Wk,
                                                const float* __restrict__ Wv,
                                                short* __restrict__ Wt){
  __shared__ float tile[64][65];
  int bx = blockIdx.x; int mat = bx >> 8; int ti = bx & 255;
  int d0 = (ti >> 4) << 6, h0 = (ti & 15) << 6;
  const float* W = (mat==0) ? Wq : (mat==1 ? Wk : Wv);
  int t = threadIdx.x;
  for (int i=0;i<16;i++){ int e = i*256 + t; int r = e>>6, c = e&63;
    tile[r][c] = W[(size_t)(d0+r)*HH + h0 + c]; }
  __syncthreads();
  for (int i=0;i<16;i++){ int e = i*256 + t; int r = e>>6, c = e&63;
    Wt[(size_t)(mat*HH + h0 + r)*DD + d0 + c] = f2bf(tile[c][r]); }
}

// ---------------- kernel 1: GEMM  C[16384 x 3072] = xb * W  (+bias), bf16 out ----
__global__ __launch_bounds__(256) void k_gemm(const short* __restrict__ Aw,
                                              const short* __restrict__ Bw,
                                              const float* __restrict__ bq,
                                              const float* __restrict__ bk,
                                              const float* __restrict__ bv,
                                              short* __restrict__ Qw,
                                              short* __restrict__ Kw,
                                              short* __restrict__ Vw){
  __shared__ short Al[128*32];
  __shared__ short Bl[128*32];
  int t = threadIdx.x; int l = t & 63; int w = t >> 6;
  int bn = blockIdx.x, bm = blockIdx.y;
  int m0 = bm << 7, c0 = bn << 7;
  f32x4 acc[4][4] = {};
  int soff = w*2048 + l*16;
  int rA0 = ((w>>1)*64 + (l&15))*32 + (l>>4)*8;
  int rB0 = ((w&1)*64 + (l&15))*32 + (l>>4)*8;
  for (int k0 = 0; k0 < DD; k0 += 32){
    __syncthreads();
    #pragma unroll
    for (int j=0;j<2;j++){
      int off = soff + j*1024;
      int row = off >> 6, ke = (off & 63) >> 1;
      GL16(Aw + (size_t)(m0+row)*DD + k0 + ke, ((char*)Al) + off);
      GL16(Bw + (size_t)(c0+row)*DD + k0 + ke, ((char*)Bl) + off);
    }
    __syncthreads();
    s16x8 af[4], bf[4];
    #pragma unroll
    for (int i=0;i<4;i++){
      af[i] = *(const s16x8*)&Al[rA0 + i*512];
      bf[i] = *(const s16x8*)&Bl[rB0 + i*512];
    }
    #pragma unroll
    for (int mi=0;mi<4;mi++)
      #pragma unroll
      for (int ni=0;ni<4;ni++)
        acc[mi][ni] = MFMA(af[mi], bf[ni], acc[mi][ni]);
  }
  int wr = w>>1, wc = w&1;
  int rg_base = m0 + wr*64;
  int cg_base = c0 + wc*64;
  #pragma unroll
  for (int ni=0;ni<4;ni++){
    int cg = cg_base + ni*16 + (l&15);
    int mat = cg >> 10, cin = cg & 1023;
    const float* bias = (mat==0) ? bq : (mat==1 ? bk : bv);
    float bval = bias[cin];
    short* Outp = (mat==0) ? Qw : (mat==1 ? Kw : Vw);
    #pragma unroll
    for (int mi=0;mi<4;mi++){
      int rg = rg_base + mi*16 + (l>>4)*4;
      #pragma unroll
      for (int i=0;i<4;i++)
        Outp[(size_t)(rg+i)*HH + cin] = f2bf(acc[mi][ni][i] + bval);
    }
  }
}

// ---------------- kernel 1b: V [b][n][h] -> Vt [b][h][n] ----------------
__global__ __launch_bounds__(256) void k_vtrans(const short* __restrict__ Vw,
                                                short* __restrict__ Vt){
  __shared__ uint16_t tile[64][65];
  int bx = blockIdx.x; int b = bx >> 9; int rem = bx & 511;
  int n0 = (rem >> 4) << 6, h0 = (rem & 15) << 6;
  int t = threadIdx.x;
  const uint16_t* vin = (const uint16_t*)Vw;
  uint16_t* vout = (uint16_t*)Vt;
  for (int i=0;i<16;i++){ int e = i*256 + t; int r = e>>6, c = e&63;
    tile[r][c] = vin[((size_t)b*NN + n0 + r)*HH + h0 + c]; }
  __syncthreads();
  for (int i=0;i<16;i++){ int e = i*256 + t; int r = e>>6, c = e&63;
    vout[((size_t)b*HH + h0 + r)*NN + n0 + c] = tile[c][r]; }
}

// ---------------- kernel 2: flash attention v3 ----------------
// 256 blocks, 512 threads = 8 waves. b = blk&7 (XCD-pinned batch); block handles
// the complementary q-tile pair {63-pair, pair} (BQ=32 each) sequentially ->
// every block does exactly 9 key-iterations (perfect balance).
// Per q-tile: Q (32x1024) staged ONCE into LDS (XOR-swizzled chunks).
// Per iteration (256 keys): wave w owns keys [w*32,w*32+32) for QK^T over full H
// (S^T in regs via mfma(K,Q)), and h-slice [w*128,(w+1)*128) for PV.
// o[2][8]=64 VGPR -> ~100 free regs let K/V global loads pipeline deep.
// 3 barriers/iteration, none inside QK^T or PV.
__global__ __launch_bounds__(512,2) void k_flash(const short* __restrict__ Qw,
                                                 const short* __restrict__ Kw,
                                                 const short* __restrict__ Vt,
                                                 float* __restrict__ out){
  __shared__ short Qc[32*1024];        // 64 KB swizzled Q tile
  __shared__ uint16_t Pl[32*256];      // 16 KB swizzled P
  __shared__ float Mred[8][32];
  __shared__ float Mfin[32], Fsc[32], Mst[32], Lfin[32];

  const int t = threadIdx.x, l = t & 63, w = t >> 6;
  const int g = l >> 4, c = l & 15;
  const int p = blockIdx.x;
  const int b = p & 7, pair = p >> 3;
  const float scale = 0.03125f;            // 1/sqrt(1024)
  const float L2E = 1.44269504088896f;
  const float NEG = -3.0e38f;

  for (int pi = 0; pi < 2; ++pi){
    const int qt = pi ? pair : (63 - pair);  // long tile first
    const int q0 = qt << 5;

    // ---- stage Q tile once (source pre-swizzled so linear LDS == swizzled layout)
    #pragma unroll
    for (int j=0;j<8;j++){
      int row = w*4 + (j>>1);                       // wave-uniform
      int u = (((j&1)*64) + l) ^ (row & 7);         // per-lane source chunk
      GL16(Qw + ((size_t)(b*NN + q0 + row))*HH + u*8,
           ((char*)Qc) + row*2048 + (j&1)*1024);
    }
    if (t < 32) Mst[t] = NEG;
    __syncthreads();                                 // drains vmcnt too

    f32x4 o[2][8] = {};
    float lp[2] = {0.f, 0.f};
    const int n_it = (q0 + 287) >> 8;
    for (int it = 0; it < n_it; ++it){
      const int kb = it*256 + w*32;
      f32x4 sp[2][2] = {};
      if (kb <= q0 + 31){
        const short* Kp  = Kw + ((size_t)(b*NN + kb + c))*HH;
        const short* Kp2 = Kp + (size_t)16*HH;
        __builtin_amdgcn_s_setprio(1);
        #pragma unroll
        for (int hs = 0; hs < 32; ++hs){
          s16x8 kf0 = *(const s16x8*)(Kp  + hs*32 + g*8);
          s16x8 kf1 = *(const s16x8*)(Kp2 + hs*32 + g*8);
          #pragma unroll
          for (int qi = 0; qi < 2; ++qi){
            s16x8 qf = *(const s16x8*)(Qc + (qi*16 + c)*1024 + (((hs*4+g) ^ (c&7))*8));
            sp[qi][0] = MFMA(kf0, qf, sp[qi][0]);    // S^T: rows=key, cols=q
            sp[qi][1] = MFMA(kf1, qf, sp[qi][1]);
          }
        }
        __builtin_amdgcn_s_setprio(0);
      }
      // ---- softmax. S^T layout: key = kb + ki*16 + g*4 + i, q = q0 + qi*16 + c.
      float rmax[2];
      #pragma unroll
      for (int qi=0;qi<2;qi++){
        int q = q0 + qi*16 + c;
        float mx = NEG;
        #pragma unroll
        for (int ki=0;ki<2;ki++)
          #pragma unroll
          for (int i=0;i<4;i++){
            int key = kb + ki*16 + g*4 + i;
            float s = (key <= q) ? sp[qi][ki][i]*scale : NEG;
            sp[qi][ki][i] = s;
            mx = fmaxf(mx, s);
          }
        mx = fmaxf(mx, __shfl_xor(mx, 16));
        mx = fmaxf(mx, __shfl_xor(mx, 32));
        rmax[qi] = mx;
      }
      if (g == 0){ Mred[w][c] = rmax[0]; Mred[w][16+c] = rmax[1]; }
      __syncthreads();
      if (t < 32){
        float mx = Mred[0][t];
        #pragma unroll
        for (int ww=1; ww<8; ww++) mx = fmaxf(mx, Mred[ww][t]);
        float mo = Mst[t], mn = fmaxf(mo, mx);
        Mst[t] = mn; Mfin[t] = mn;
        Fsc[t] = exp2f((mo - mn)*L2E);
      }
      __syncthreads();
      // exp + P write (swizzled 16B chunks) + per-wave row-sum
      #pragma unroll
      for (int qi=0;qi<2;qi++){
        float mf = Mfin[qi*16 + c];
        float sum = 0.f;
        #pragma unroll
        for (int ki=0;ki<2;ki++){
          short4 pk;
          #pragma unroll
          for (int i=0;i<4;i++){
            float pv = exp2f((sp[qi][ki][i] - mf)*L2E);
            sum += pv;
            ((short*)&pk)[i] = f2bf(pv);
          }
          int chunk = (w*4 + ki*2 + (g>>1)) ^ (c & 7);
          *(short4*)((char*)Pl + (qi*16 + c)*512 + chunk*16 + (g&1)*8) = pk;
        }
        sum += __shfl_xor(sum, 16);
        sum += __shfl_xor(sum, 32);
        lp[qi] = lp[qi]*Fsc[qi*16 + c] + sum;
      }
      // rescale O (O rows: q = qi*16 + g*4 + i)
      #pragma unroll
      for (int qi=0;qi<2;qi++){
        f32x4 fs = *(const f32x4*)&Fsc[qi*16 + g*4];
        #pragma unroll
        for (int hi=0;hi<8;hi++)
          #pragma unroll
          for (int i=0;i<4;i++) o[qi][hi][i] *= fs[i];
      }
      __syncthreads();                      // P visible
      // ---- PV: O[32 x 128] += P[32 x kt_lim*32] * V ----
      int kt_lim = ((q0 + 31 - it*256) >> 5) + 1;
      if (kt_lim > 8) kt_lim = 8;
      __builtin_amdgcn_s_setprio(1);
      for (int kt = 0; kt < kt_lim; ++kt){
        s16x8 pf[2];
        #pragma unroll
        for (int qi=0;qi<2;qi++)
          pf[qi] = *(const s16x8*)((char*)Pl + (qi*16 + c)*512 + (((kt*4+g) ^ (c&7))*16));
        #pragma unroll
        for (int hi=0;hi<8;hi++){
          s16x8 vf = *(const s16x8*)(Vt + ((size_t)(b*HH + w*128 + hi*16 + c))*NN
                                        + it*256 + kt*32 + g*8);
          #pragma unroll
          for (int qi=0;qi<2;qi++)
            o[qi][hi] = MFMA(pf[qi], vf, o[qi][hi]);
        }
      }
      __builtin_amdgcn_s_setprio(0);
      // no barrier needed: next P write is 2 barriers away
    }
    // ---- epilogue: reduce l across waves, divide, store ----
    if (g == 0){ Mred[w][c] = lp[0]; Mred[w][16+c] = lp[1]; }
    __syncthreads();
    if (t < 32){
      float s = 0.f;
      #pragma unroll
      for (int ww=0; ww<8; ww++) s += Mred[ww][t];
      Lfin[t] = 1.0f / s;
    }
    __syncthreads();
    #pragma unroll
    for (int qi=0;qi<2;qi++){
      f32x4 li = *(const f32x4*)&Lfin[qi*16 + g*4];
      #pragma unroll
      for (int hi=0;hi<8;hi++)
        #pragma unroll
        for (int i=0;i<4;i++)
          out[((size_t)(b*NN + q0 + qi*16 + g*4 + i))*HH + w*128 + hi*16 + c]
            = o[qi][hi][i] * li[i];
    }
  }
}

extern "C" void kernel_launch(void* const* d_in, const int* in_sizes, int n_in,
                              void* d_out, int out_size, void* d_ws, size_t ws_size,
                              hipStream_t stream) {
  const float* x  = (const float*)d_in[0];
  const float* Wq = (const float*)d_in[1];
  const float* bq = (const float*)d_in[2];
  const float* Wk = (const float*)d_in[3];
  const float* bk = (const float*)d_in[4];
  const float* Wv = (const float*)d_in[5];
  const float* bv = (const float*)d_in[6];
  char* ws = (char*)d_ws;
  short* xb = (short*)(ws);                         // 33,554,432
  short* Wt = (short*)(ws + 33554432u);             //  6,291,456
  short* Qw = (short*)(ws + 39845888u);             // 33,554,432
  short* Kw = (short*)(ws + 73400320u);             // 33,554,432
  short* Vw = (short*)(ws + 106954752u);            // 33,554,432
  short* Vt = (short*)(ws + 140509184u);            // 33,554,432

  k_conv_x<<<8192, 256, 0, stream>>>(x, xb);
  k_conv_w<<<768, 256, 0, stream>>>(Wq, Wk, Wv, Wt);
  k_gemm<<<dim3(24,128), 256, 0, stream>>>(xb, Wt, bq, bk, bv, Qw, Kw, Vw);
  k_vtrans<<<4096, 256, 0, stream>>>(Vw, Vt);
  k_flash<<<256, 512, 0, stream>>>(Qw, Kw, Vt, (float*)d_out);
}